// Round 1
// 655.478 us; speedup vs baseline: 1.0901x; 1.0901x over previous
//
#include <hip/hip_runtime.h>
#include <hip/hip_bf16.h>
#include <math.h>

// Problem constants
constexpr int CB   = 2;      // batch
constexpr int CS   = 4096;   // seq
constexpr int CD   = 1024;   // d_model
constexpr int CH   = 16;     // heads
constexpr int CDH  = 64;     // head dim
constexpr int CR   = 4;      // hash rounds
constexpr int CC   = 64;     // chunk length
constexpr int CNCH = 64;     // num chunks
constexpr int CDFF = 4096;
constexpr int CBS  = CB * CS;        // 8192 rows
constexpr int CBHS = CB * CH * CS;   // 131072

typedef __attribute__((ext_vector_type(8))) short short8;
typedef __attribute__((ext_vector_type(4))) short short4v;
typedef __attribute__((ext_vector_type(4))) float f32x4;

// HW bf16 conversion: gfx950 lowers fptrunc f32->bf16 to v_cvt_pk_bf16_f32.
__device__ inline unsigned short f2bf(float f) {
    __bf16 h = (__bf16)f;
    union { __bf16 h; unsigned short u; } c; c.h = h;
    return c.u;
}
// paired conversion -> one packed u32 (compiler fuses to single v_cvt_pk_bf16_f32)
__device__ inline unsigned int cvt2(float a, float b) {
    return (unsigned int)f2bf(a) | ((unsigned int)f2bf(b) << 16);
}
__device__ inline float bf2f(unsigned short h) {
    union { float f; unsigned int u; } a; a.u = ((unsigned int)h) << 16; return a.f;
}

#define AS3 __attribute__((address_space(3)))
#define AS1 __attribute__((address_space(1)))
__device__ inline void gload16(const unsigned short* g, unsigned short* l) {
    __builtin_amdgcn_global_load_lds((const AS1 unsigned int*)g,
                                     (AS3 unsigned int*)l, 16, 0, 0);
}

// 8-short load from 8B-aligned (not necessarily 16B-aligned) LDS address
__device__ inline short8 ld_short8_u(const unsigned short* p) {
    short4v a = *(const short4v*)p;
    short4v b = *(const short4v*)(p + 4);
    short8 r;
    r[0] = a[0]; r[1] = a[1]; r[2] = a[2]; r[3] = a[3];
    r[4] = b[0]; r[5] = b[1]; r[6] = b[2]; r[7] = b[3];
    return r;
}

// ---------------- LayerNorm: one block per row; bf16 hi (+ optional lo) -----
__global__ __launch_bounds__(256) void ln_kernel(const float* __restrict__ x,
        const float* __restrict__ g, const float* __restrict__ bta,
        unsigned short* __restrict__ out16, unsigned short* __restrict__ out16lo) {
    int row = blockIdx.x;
    int t = threadIdx.x;
    const float* xr = x + (size_t)row * CD;
    float4 v = *(const float4*)(xr + t * 4);
    float s  = v.x + v.y + v.z + v.w;
    float ss = v.x * v.x + v.y * v.y + v.z * v.z + v.w * v.w;
    #pragma unroll
    for (int off = 1; off < 64; off <<= 1) {
        s  += __shfl_xor(s, off);
        ss += __shfl_xor(ss, off);
    }
    __shared__ float ws_[4], wss_[4];
    int wid = t >> 6;
    if ((t & 63) == 0) { ws_[wid] = s; wss_[wid] = ss; }
    __syncthreads();
    s  = ws_[0] + ws_[1] + ws_[2] + ws_[3];
    ss = wss_[0] + wss_[1] + wss_[2] + wss_[3];
    float mean = s * (1.0f / CD);
    float var  = ss * (1.0f / CD) - mean * mean;
    float rstd = rsqrtf(var + 1e-5f);
    float4 gv = *(const float4*)(g + t * 4);
    float4 bv = *(const float4*)(bta + t * 4);
    float4 o;
    o.x = (v.x - mean) * rstd * gv.x + bv.x;
    o.y = (v.y - mean) * rstd * gv.y + bv.y;
    o.z = (v.z - mean) * rstd * gv.z + bv.z;
    o.w = (v.w - mean) * rstd * gv.w + bv.w;
    ushort4 h; h.x = f2bf(o.x); h.y = f2bf(o.y); h.z = f2bf(o.z); h.w = f2bf(o.w);
    *(ushort4*)(out16 + (size_t)row * CD + t * 4) = h;
    if (out16lo) {
        ushort4 lo;
        lo.x = f2bf(o.x - bf2f(h.x)); lo.y = f2bf(o.y - bf2f(h.y));
        lo.z = f2bf(o.z - bf2f(h.z)); lo.w = f2bf(o.w - bf2f(h.w));
        *(ushort4*)(out16lo + (size_t)row * CD + t * 4) = lo;
    }
}

// ------- weight transpose + fp32->bf16 (hi + optional lo): W[K][N]->WT[N][K]
__global__ __launch_bounds__(256) void wtrans_kernel(const float* __restrict__ W,
        unsigned short* __restrict__ WT, unsigned short* __restrict__ WTlo,
        int K, int N) {
    __shared__ float tile[64][65];
    int n0 = blockIdx.x * 64, k0 = blockIdx.y * 64;
    int tid = threadIdx.x;
    int r = tid >> 4, c4 = tid & 15;
    #pragma unroll
    for (int it = 0; it < 4; ++it) {
        int row = r + it * 16;
        float4 v = *(const float4*)(W + (size_t)(k0 + row) * N + n0 + c4 * 4);
        tile[row][c4 * 4 + 0] = v.x; tile[row][c4 * 4 + 1] = v.y;
        tile[row][c4 * 4 + 2] = v.z; tile[row][c4 * 4 + 3] = v.w;
    }
    __syncthreads();
    #pragma unroll
    for (int it = 0; it < 4; ++it) {
        int nrow = r + it * 16;
        float f0 = tile[c4 * 4 + 0][nrow], f1 = tile[c4 * 4 + 1][nrow];
        float f2 = tile[c4 * 4 + 2][nrow], f3 = tile[c4 * 4 + 3][nrow];
        ushort4 h;
        h.x = f2bf(f0); h.y = f2bf(f1); h.z = f2bf(f2); h.w = f2bf(f3);
        *(ushort4*)(WT + (size_t)(n0 + nrow) * K + k0 + c4 * 4) = h;
        if (WTlo) {
            ushort4 lo;
            lo.x = f2bf(f0 - bf2f(h.x)); lo.y = f2bf(f1 - bf2f(h.y));
            lo.z = f2bf(f2 - bf2f(h.z)); lo.w = f2bf(f3 - bf2f(h.w));
            *(ushort4*)(WTlo + (size_t)(n0 + nrow) * K + k0 + c4 * 4) = lo;
        }
    }
}

// ---------------- bf16 MFMA GEMM: C[M][N] = A[M][K] @ BT[N][K]^T ------------
// BM = 128 or 64 (N-tile fixed at 128). XCD-chunked block swizzle.
template<int EPI, int BM>
__global__ __launch_bounds__(256) void gemm_bf16(const unsigned short* __restrict__ A,
        const unsigned short* __restrict__ BT, const float* __restrict__ bias,
        const float* __restrict__ res, void* __restrict__ outp,
        int M, int N, int K) {
    constexpr int SA  = BM / 64;   // A-staging chunks per wave
    constexpr int MI2 = BM / 32;   // A fragments per wave
    __shared__ __align__(16) unsigned short As[BM * 32];
    __shared__ __align__(16) unsigned short Bs[128 * 32];
    int tid = threadIdx.x;
    int w = tid >> 6, l = tid & 63;
    // XCD-aware chunked swizzle (bijective since nwg % 8 == 0 for all launches)
    int nwg = gridDim.x * gridDim.y;
    int lid = blockIdx.y * gridDim.x + blockIdx.x;
    if (!(nwg & 7)) lid = (lid & 7) * (nwg >> 3) + (lid >> 3);
    int m0 = (lid / gridDim.x) * BM, n0 = (lid % gridDim.x) * 128;
    int wm = (w >> 1) * (BM / 2), wn = (w & 1) * 64;

    const unsigned short* gA[SA]; const unsigned short* gB[2];
    unsigned short* ldsA[SA]; unsigned short* ldsB[2];
    int gchunk = (l & 3) ^ ((l >> 3) & 3);
    #pragma unroll
    for (int s = 0; s < SA; ++s) {
        int j = w * SA + s;
        int R = j * 16 + (l >> 2);
        gA[s] = A + (size_t)(m0 + R) * K + gchunk * 8;
        ldsA[s] = As + j * 512;
    }
    #pragma unroll
    for (int s = 0; s < 2; ++s) {
        int j = w * 2 + s;
        int R = j * 16 + (l >> 2);
        gB[s] = BT + (size_t)(n0 + R) * K + gchunk * 8;
        ldsB[s] = Bs + j * 512;
    }
    int p = (l >> 4) ^ (((l & 15) >> 1) & 3);
    int aoff = (wm + (l & 15)) * 32 + p * 8;
    int boff = (wn + (l & 15)) * 32 + p * 8;

    f32x4 acc[MI2][4];
    #pragma unroll
    for (int i = 0; i < MI2; i++)
        #pragma unroll
        for (int j = 0; j < 4; j++) acc[i][j] = (f32x4)(0.f);

    for (int k0 = 0; k0 < K; k0 += 32) {
        #pragma unroll
        for (int s = 0; s < SA; ++s) gload16(gA[s] + k0, ldsA[s]);
        gload16(gB[0] + k0, ldsB[0]);
        gload16(gB[1] + k0, ldsB[1]);
        __syncthreads();
        short8 af[MI2], bf[4];
        #pragma unroll
        for (int im = 0; im < MI2; ++im) af[im] = *(const short8*)(As + aoff + im * 512);
        #pragma unroll
        for (int in = 0; in < 4; ++in) bf[in] = *(const short8*)(Bs + boff + in * 512);
        #pragma unroll
        for (int im = 0; im < MI2; ++im)
            #pragma unroll
            for (int in = 0; in < 4; ++in)
                acc[im][in] = __builtin_amdgcn_mfma_f32_16x16x32_bf16(
                    af[im], bf[in], acc[im][in], 0, 0, 0);
        __syncthreads();
    }

    float bv[4];
    if (EPI == 1 || EPI == 2) {
        #pragma unroll
        for (int in = 0; in < 4; ++in) bv[in] = bias[n0 + wn + in * 16 + (l & 15)];
    }
    #pragma unroll
    for (int im = 0; im < MI2; ++im) {
        #pragma unroll
        for (int in = 0; in < 4; ++in) {
            int n = n0 + wn + in * 16 + (l & 15);
            #pragma unroll
            for (int r = 0; r < 4; ++r) {
                int m = m0 + wm + im * 16 + (l >> 4) * 4 + r;
                float v = acc[im][in][r];
                if (EPI == 1) {
                    v = fmaxf(v + bv[in], 0.f);
                    ((unsigned short*)outp)[(size_t)m * N + n] = f2bf(v);
                } else if (EPI == 5) {
                    ((unsigned short*)outp)[(size_t)m * N + n] = f2bf(v);
                } else {
                    if (EPI == 2) v += bv[in] + res[(size_t)m * N + n];
                    if (EPI == 3) v += res[(size_t)m * N + n];
                    ((float*)outp)[(size_t)m * N + n] = v;
                }
            }
        }
    }
}

// -------- split-bf16 MFMA GEMM (hi/lo): C = (Ah+Al) @ (Bh+Bl)^T -------------
// fp32 out (bucketing) + bf16 out (attention). acc = Ah@Bh + Al@Bh + Ah@Bl.
template<int BM>
__global__ __launch_bounds__(256) void gemm_bf16split(
        const unsigned short* __restrict__ Ah, const unsigned short* __restrict__ Al,
        const unsigned short* __restrict__ BTh, const unsigned short* __restrict__ BTl,
        float* __restrict__ outp, unsigned short* __restrict__ out16,
        int M, int N, int K) {
    constexpr int SA  = BM / 64;
    constexpr int MI2 = BM / 32;
    __shared__ __align__(16) unsigned short Ash[BM * 32];
    __shared__ __align__(16) unsigned short Asl[BM * 32];
    __shared__ __align__(16) unsigned short Bsh[128 * 32];
    __shared__ __align__(16) unsigned short Bsl[128 * 32];
    int tid = threadIdx.x;
    int w = tid >> 6, l = tid & 63;
    int nwg = gridDim.x * gridDim.y;
    int lid = blockIdx.y * gridDim.x + blockIdx.x;
    if (!(nwg & 7)) lid = (lid & 7) * (nwg >> 3) + (lid >> 3);
    int m0 = (lid / gridDim.x) * BM, n0 = (lid % gridDim.x) * 128;
    int wm = (w >> 1) * (BM / 2), wn = (w & 1) * 64;

    size_t goffA[SA]; size_t goffB[2];
    unsigned short* ldsAh[SA]; unsigned short* ldsAl[SA];
    unsigned short* ldsBh[2]; unsigned short* ldsBl[2];
    int gchunk = (l & 3) ^ ((l >> 3) & 3);
    #pragma unroll
    for (int s = 0; s < SA; ++s) {
        int j = w * SA + s;
        int R = j * 16 + (l >> 2);
        goffA[s] = (size_t)(m0 + R) * K + gchunk * 8;
        ldsAh[s] = Ash + j * 512; ldsAl[s] = Asl + j * 512;
    }
    #pragma unroll
    for (int s = 0; s < 2; ++s) {
        int j = w * 2 + s;
        int R = j * 16 + (l >> 2);
        goffB[s] = (size_t)(n0 + R) * K + gchunk * 8;
        ldsBh[s] = Bsh + j * 512; ldsBl[s] = Bsl + j * 512;
    }
    int p = (l >> 4) ^ (((l & 15) >> 1) & 3);
    int aoff = (wm + (l & 15)) * 32 + p * 8;
    int boff = (wn + (l & 15)) * 32 + p * 8;

    f32x4 acc[MI2][4];
    #pragma unroll
    for (int i = 0; i < MI2; i++)
        #pragma unroll
        for (int j = 0; j < 4; j++) acc[i][j] = (f32x4)(0.f);

    for (int k0 = 0; k0 < K; k0 += 32) {
        #pragma unroll
        for (int s = 0; s < SA; ++s) {
            gload16(Ah + goffA[s] + k0, ldsAh[s]);
            gload16(Al + goffA[s] + k0, ldsAl[s]);
        }
        #pragma unroll
        for (int s = 0; s < 2; ++s) {
            gload16(BTh + goffB[s] + k0, ldsBh[s]);
            gload16(BTl + goffB[s] + k0, ldsBl[s]);
        }
        __syncthreads();
        short8 afh[MI2], afl[MI2], bfh[4], bfl[4];
        #pragma unroll
        for (int im = 0; im < MI2; ++im) {
            afh[im] = *(const short8*)(Ash + aoff + im * 512);
            afl[im] = *(const short8*)(Asl + aoff + im * 512);
        }
        #pragma unroll
        for (int in = 0; in < 4; ++in) {
            bfh[in] = *(const short8*)(Bsh + boff + in * 512);
            bfl[in] = *(const short8*)(Bsl + boff + in * 512);
        }
        #pragma unroll
        for (int im = 0; im < MI2; ++im)
            #pragma unroll
            for (int in = 0; in < 4; ++in) {
                acc[im][in] = __builtin_amdgcn_mfma_f32_16x16x32_bf16(
                    afh[im], bfh[in], acc[im][in], 0, 0, 0);
                acc[im][in] = __builtin_amdgcn_mfma_f32_16x16x32_bf16(
                    afl[im], bfh[in], acc[im][in], 0, 0, 0);
                acc[im][in] = __builtin_amdgcn_mfma_f32_16x16x32_bf16(
                    afh[im], bfl[in], acc[im][in], 0, 0, 0);
            }
        __syncthreads();
    }

    #pragma unroll
    for (int im = 0; im < MI2; ++im)
        #pragma unroll
        for (int in = 0; in < 4; ++in) {
            int n = n0 + wn + in * 16 + (l & 15);
            #pragma unroll
            for (int r = 0; r < 4; ++r) {
                int m = m0 + wm + im * 16 + (l >> 4) * 4 + r;
                float v = acc[im][in][r];
                outp[(size_t)m * N + n] = v;
                out16[(size_t)m * N + n] = f2bf(v);
            }
        }
}

// ---------------- fp32 tiled GEMM (rotation + bucket argmax only) -----------
template<int EPI>
__global__ __launch_bounds__(256) void gemm_f32(const float* __restrict__ A,
        const float* __restrict__ W, float* __restrict__ out,
        int M, int N, int K) {
    __shared__ __align__(16) float As[16][132];
    __shared__ __align__(16) float Bs[16][132];
    int tid = threadIdx.x;
    int n0 = blockIdx.x * 128;
    int m0 = blockIdx.y * 128;
    int ty = tid >> 4, tx = tid & 15;
    float acc[8][8];
    #pragma unroll
    for (int i = 0; i < 8; i++)
        #pragma unroll
        for (int j = 0; j < 8; j++) acc[i][j] = 0.f;

    for (int k0 = 0; k0 < K; k0 += 16) {
        #pragma unroll
        for (int it = 0; it < 2; ++it) {
            int f4 = tid + it * 256;
            int row = f4 >> 2, c4 = f4 & 3;
            float4 av = *(const float4*)(A + (size_t)(m0 + row) * K + k0 + c4 * 4);
            As[c4 * 4 + 0][row] = av.x;
            As[c4 * 4 + 1][row] = av.y;
            As[c4 * 4 + 2][row] = av.z;
            As[c4 * 4 + 3][row] = av.w;
        }
        #pragma unroll
        for (int it = 0; it < 2; ++it) {
            int f4 = tid + it * 256;
            int kr = f4 >> 5, c4 = f4 & 31;
            *(float4*)(&Bs[kr][c4 * 4]) =
                *(const float4*)(W + (size_t)(k0 + kr) * N + n0 + c4 * 4);
        }
        __syncthreads();
        #pragma unroll
        for (int kk = 0; kk < 16; ++kk) {
            float4 a0 = *(const float4*)(&As[kk][ty * 8]);
            float4 a1 = *(const float4*)(&As[kk][ty * 8 + 4]);
            float4 b0 = *(const float4*)(&Bs[kk][tx * 8]);
            float4 b1 = *(const float4*)(&Bs[kk][tx * 8 + 4]);
            float am[8] = {a0.x, a0.y, a0.z, a0.w, a1.x, a1.y, a1.z, a1.w};
            float bn[8] = {b0.x, b0.y, b0.z, b0.w, b1.x, b1.y, b1.z, b1.w};
            #pragma unroll
            for (int i = 0; i < 8; i++)
                #pragma unroll
                for (int j = 0; j < 8; j++)
                    acc[i][j] = fmaf(am[i], bn[j], acc[i][j]);
        }
        __syncthreads();
    }

    if (EPI == 4) {
        int* ibuck = (int*)out;
        int q = tx & 3, r = tx >> 2;      // col = r*32 + q*8 + j
        #pragma unroll
        for (int i = 0; i < 8; i++) {
            int m = m0 + ty * 8 + i;
            float bestP = -3.4e38f, bestN = -3.4e38f;
            int biP = 0, biN = 0;
            #pragma unroll
            for (int j = 0; j < 8; j++) {
                float v = acc[i][j];
                if ( v > bestP) { bestP =  v; biP = q * 8 + j; }
                if (-v > bestN) { bestN = -v; biN = q * 8 + j; }
            }
            #pragma unroll
            for (int off = 1; off < 4; off <<= 1) {
                float oP = __shfl_xor(bestP, off); int oiP = __shfl_xor(biP, off);
                float oN = __shfl_xor(bestN, off); int oiN = __shfl_xor(biN, off);
                if (oP > bestP || (oP == bestP && oiP < biP)) { bestP = oP; biP = oiP; }
                if (oN > bestN || (oN == bestN && oiN < biN)) { bestN = oN; biN = oiN; }
            }
            if (q == 0) {
                int bi = (bestP >= bestN) ? biP : (biN + 32);
                int hh = m & 15, ss2 = (m >> 4) & (CS - 1), bb2 = m >> 16;
                ibuck[((size_t)((r * CB + bb2) * CH + hh)) * CS + ss2] = bi;
            }
        }
        return;
    }

    #pragma unroll
    for (int i = 0; i < 8; i++) {
        int m = m0 + ty * 8 + i;
        #pragma unroll
        for (int j4 = 0; j4 < 2; j4++) {
            int n = n0 + tx * 8 + j4 * 4;
            float4 v;
            v.x = acc[i][j4 * 4 + 0]; v.y = acc[i][j4 * 4 + 1];
            v.z = acc[i][j4 * 4 + 2]; v.w = acc[i][j4 * 4 + 3];
            *(float4*)(out + (size_t)m * N + n) = v;
        }
    }
}

// ---------------- stable counting sort per (r,b,h): one wave ----------------
__global__ __launch_bounds__(64) void sort_kernel(const int* __restrict__ buckets,
                                                  int* __restrict__ sorted_pos) {
    int g = blockIdx.x;                  // rbh
    const int* bk = buckets + (size_t)g * CS;
    __shared__ int hist[64][65];
    __shared__ int bstart[64];
    int t = threadIdx.x;
    #pragma unroll
    for (int i = 0; i < 64; i++) hist[t][i] = 0;
    __syncthreads();
    int base = t * 64;
    for (int i = 0; i < 64; i++) { int b = bk[base + i]; hist[t][b]++; }
    __syncthreads();
    int run = 0;
    for (int tt = 0; tt < 64; tt++) {
        int c = hist[tt][t];
        hist[tt][t] = run;
        run += c;
    }
    int x = run;
    #pragma unroll
    for (int off = 1; off < 64; off <<= 1) {
        int y = __shfl_up(x, off);
        if (t >= off) x += y;
    }
    bstart[t] = x - run;
    __syncthreads();
    for (int i = 0; i < 64; i++) {
        int b = bk[base + i];
        int rank = bstart[b] + hist[t][b];
        hist[t][b]++;
        sorted_pos[(size_t)g * CS + rank] = base + i;
    }
}

// ---------------- chunked LSH attention (bf16 MFMA, bf16 inputs) ------------
__global__ __launch_bounds__(256) void attn_kernel(const unsigned short* __restrict__ qk16,
        const unsigned short* __restrict__ v16, const int* __restrict__ buckets,
        const int* __restrict__ sorted, unsigned short* __restrict__ o_all,
        float* __restrict__ l_all) {
    int n  = blockIdx.x;
    int r  = blockIdx.y;
    int bh = blockIdx.z;
    int b = bh >> 4, h = bh & 15;
    int rbh = (r * CB + b) * CH + h;
    int tid = threadIdx.x;
    int w = tid >> 6, l = tid & 63;
    int l4 = l & 15, qd = l >> 4;

    __shared__ int pk[128];
    __shared__ int bkk[128];
    __shared__ __align__(16) unsigned short Ks[128 * 72];   // K-hat [kk][d]
    __shared__ __align__(16) unsigned short Ps[64 * 132];   // P [m][kk]
    __shared__ __align__(16) unsigned short VsT[64 * 132];  // V^T [d][kk]

    int prev = (n + CNCH - 1) & (CNCH - 1);
    if (tid < 128) {
        int i = tid & 63;
        int ch = (tid < 64) ? n : prev;
        int p = sorted[(size_t)rbh * CS + ch * CC + i];
        pk[tid] = p;
        bkk[tid] = buckets[(size_t)rbh * CS + p];
    }
    __syncthreads();

    const unsigned short* qbase = qk16 + (size_t)b * CS * CD + h * 64;
    const unsigned short* vbase = v16  + (size_t)b * CS * CD + h * 64;

    // K staging: load bf16 qk row, L2-normalize, store bf16 (paired cvt)
    #pragma unroll
    for (int it = 0; it < 8; ++it) {
        int f4 = tid + it * 256;            // 0..2047
        int kk = f4 >> 4, d4 = f4 & 15;
        ushort4 hv = *(const ushort4*)(qbase + (size_t)pk[kk] * CD + d4 * 4);
        float x0 = bf2f(hv.x), x1 = bf2f(hv.y), x2 = bf2f(hv.z), x3 = bf2f(hv.w);
        float ss = x0 * x0 + x1 * x1 + x2 * x2 + x3 * x3;
        ss += __shfl_xor(ss, 1); ss += __shfl_xor(ss, 2);
        ss += __shfl_xor(ss, 4); ss += __shfl_xor(ss, 8);
        float rn = __builtin_amdgcn_rcpf(sqrtf(ss) + 1e-6f);
        uint2 kp;
        kp.x = cvt2(x0 * rn, x1 * rn);
        kp.y = cvt2(x2 * rn, x3 * rn);
        *(uint2*)&Ks[kk * 72 + d4 * 4] = kp;
    }
    // V staging: already bf16 — pack two rows per u32, zero conversions
    #pragma unroll
    for (int it = 0; it < 16; ++it) {
        int kkp = w * 16 + it;              // 0..63 (pair index)
        int r0 = pk[2 * kkp], r1 = pk[2 * kkp + 1];
        unsigned int u0 = vbase[(size_t)r0 * CD + l];
        unsigned int u1 = vbase[(size_t)r1 * CD + l];
        *(unsigned int*)&VsT[l * 132 + 2 * kkp] = u0 | (u1 << 16);
    }
    // Q fragments: direct bf16 16B loads, zero conversions
    int mstrip = w * 16;
    const unsigned short* qptr = qbase + (size_t)pk[mstrip + l4] * CD + qd * 8;
    short8 afA = *(const short8*)(qptr);
    short8 afB = *(const short8*)(qptr + 32);
    __syncthreads();

    f32x4 sa[8];
    #pragma unroll
    for (int t = 0; t < 8; ++t) sa[t] = (f32x4)(0.f);
    #pragma unroll
    for (int t = 0; t < 8; ++t) {
        const unsigned short* kb = &Ks[(t * 16 + l4) * 72 + qd * 8];
        short8 b0 = *(const short8*)(kb);
        short8 b1 = *(const short8*)(kb + 32);
        sa[t] = __builtin_amdgcn_mfma_f32_16x16x32_bf16(afA, b0, sa[t], 0, 0, 0);
        sa[t] = __builtin_amdgcn_mfma_f32_16x16x32_bf16(afB, b1, sa[t], 0, 0, 0);
    }

    int rowb[4], rowp[4];
    #pragma unroll
    for (int rr = 0; rr < 4; ++rr) {
        int m = mstrip + 4 * qd + rr;
        rowb[rr] = bkk[m]; rowp[rr] = pk[m];
    }
    float mx[4] = {-3.4e38f, -3.4e38f, -3.4e38f, -3.4e38f};
    #pragma unroll
    for (int t = 0; t < 8; ++t) {
        int cb = bkk[t * 16 + l4], cp = pk[t * 16 + l4];
        #pragma unroll
        for (int rr = 0; rr < 4; ++rr) {
            float v = sa[t][rr] * 0.125f;
            if (rowb[rr] != cb) v = -1e9f;
            if (rowp[rr] == cp) v = -1e5f;
            sa[t][rr] = v;
            mx[rr] = fmaxf(mx[rr], v);
        }
    }
    #pragma unroll
    for (int rr = 0; rr < 4; ++rr) {
        mx[rr] = fmaxf(mx[rr], __shfl_xor(mx[rr], 1));
        mx[rr] = fmaxf(mx[rr], __shfl_xor(mx[rr], 2));
        mx[rr] = fmaxf(mx[rr], __shfl_xor(mx[rr], 4));
        mx[rr] = fmaxf(mx[rr], __shfl_xor(mx[rr], 8));
    }
    float sum[4] = {0.f, 0.f, 0.f, 0.f};
    #pragma unroll
    for (int t = 0; t < 8; ++t)
        #pragma unroll
        for (int rr = 0; rr < 4; ++rr) {
            float e = __expf(sa[t][rr] - mx[rr]);
            sa[t][rr] = e;
            sum[rr] += e;
        }
    #pragma unroll
    for (int rr = 0; rr < 4; ++rr) {
        sum[rr] += __shfl_xor(sum[rr], 1);
        sum[rr] += __shfl_xor(sum[rr], 2);
        sum[rr] += __shfl_xor(sum[rr], 4);
        sum[rr] += __shfl_xor(sum[rr], 8);
    }
    if (l4 == 0) {
        #pragma unroll
        for (int rr = 0; rr < 4; ++rr)
            l_all[(size_t)rbh * CS + rowp[rr]] = mx[rr] + __logf(sum[rr]);
    }

    float rs[4];
    #pragma unroll
    for (int rr = 0; rr < 4; ++rr) rs[rr] = __builtin_amdgcn_rcpf(sum[rr]);
    // P -> bf16 via paired conversions (rows rr0/rr1 and rr2/rr3 share a cvt)
    #pragma unroll
    for (int t = 0; t < 8; ++t) {
        unsigned int a01 = cvt2(sa[t][0] * rs[0], sa[t][1] * rs[1]);
        unsigned int a23 = cvt2(sa[t][2] * rs[2], sa[t][3] * rs[3]);
        int base = (mstrip + 4 * qd) * 132 + t * 16 + l4;
        Ps[base]       = (unsigned short)(a01 & 0xffffu);
        Ps[base + 132] = (unsigned short)(a01 >> 16);
        Ps[base + 264] = (unsigned short)(a23 & 0xffffu);
        Ps[base + 396] = (unsigned short)(a23 >> 16);
    }

    f32x4 oa[4];
    #pragma unroll
    for (int nt = 0; nt < 4; ++nt) oa[nt] = (f32x4)(0.f);
    #pragma unroll
    for (int ks = 0; ks < 4; ++ks) {
        short8 ap = ld_short8_u(&Ps[(mstrip + l4) * 132 + ks * 32 + qd * 8]);
        #pragma unroll
        for (int nt = 0; nt < 4; ++nt) {
            short8 bv = ld_short8_u(&VsT[(nt * 16 + l4) * 132 + ks * 32 + qd * 8]);
            oa[nt] = __builtin_amdgcn_mfma_f32_16x16x32_bf16(ap, bv, oa[nt], 0, 0, 0);
        }
    }
    size_t ob = (size_t)rbh * CS;
    #pragma unroll
    for (int nt = 0; nt < 4; ++nt) {
        unsigned int a01 = cvt2(oa[nt][0], oa[nt][1]);
        unsigned int a23 = cvt2(oa[nt][2], oa[nt][3]);
        o_all[(ob + rowp[0]) * CDH + nt * 16 + l4] = (unsigned short)(a01 & 0xffffu);
        o_all[(ob + rowp[1]) * CDH + nt * 16 + l4] = (unsigned short)(a01 >> 16);
        o_all[(ob + rowp[2]) * CDH + nt * 16 + l4] = (unsigned short)(a23 & 0xffffu);
        o_all[(ob + rowp[3]) * CDH + nt * 16 + l4] = (unsigned short)(a23 >> 16);
    }
}

// ---------------- combine rounds: softmax over R of logsumexp; bf16 out -----
__global__ __launch_bounds__(256) void combine_kernel(const unsigned short* __restrict__ o_all,
        const float* __restrict__ l_all, unsigned short* __restrict__ attnout16) {
    int idx = blockIdx.x * 256 + threadIdx.x;
    int d = idx & 63, bhs = idx >> 6;
    int s2 = bhs & (CS - 1), bh = bhs >> 12, h = bh & 15, b = bh >> 4;
    float lr[4];
    #pragma unroll
    for (int r = 0; r < CR; r++) lr[r] = l_all[(size_t)r * CBHS + bhs];
    float m = fmaxf(fmaxf(lr[0], lr[1]), fmaxf(lr[2], lr[3]));
    float w[4], sum = 0.f;
    #pragma unroll
    for (int r = 0; r < CR; r++) { w[r] = __expf(lr[r] - m); sum += w[r]; }
    float acc = 0.f;
    #pragma unroll
    for (int r = 0; r < CR; r++)
        acc += w[r] * bf2f(o_all[((size_t)r * CBHS + bhs) * CDH + d]);
    acc *= __builtin_amdgcn_rcpf(sum);
    attnout16[((size_t)(b * CS + s2)) * CD + h * 64 + d] = f2bf(acc);
}

extern "C" void kernel_launch(void* const* d_in, const int* in_sizes, int n_in,
                              void* d_out, int out_size, void* d_ws, size_t ws_size,
                              hipStream_t stream) {
    const float* x1   = (const float*)d_in[0];
    const float* x2   = (const float*)d_in[1];
    const float* Wqk  = (const float*)d_in[2];
    const float* Wv   = (const float*)d_in[3];
    const float* Wo   = (const float*)d_in[4];
    const float* ln1g = (const float*)d_in[5];
    const float* ln1b = (const float*)d_in[6];
    const float* W1   = (const float*)d_in[7];
    const float* bf1  = (const float*)d_in[8];
    const float* W2   = (const float*)d_in[9];
    const float* bf2  = (const float*)d_in[10];
    const float* ln2g = (const float*)d_in[11];
    const float* ln2b = (const float*)d_in[12];
    const float* rot  = (const float*)d_in[13];   // [64][128] row-major

    unsigned short* bufA16   = (unsigned short*)d_ws;          // ln1 hi bf16
    unsigned short* bufA16lo = bufA16 + (size_t)CBS * CD;      // ln1 lo bf16
    float* bufB = (float*)(bufA16lo + (size_t)CBS * CD);       // qk fp32
    float* bufC = bufB + (size_t)CBS * CD;                     // v16 + qk16 (bf16)
    unsigned short* v16  = (unsigned short*)bufC;              // v bf16
    unsigned short* qk16 = v16 + (size_t)CBS * CD;             // qk bf16
    unsigned short* o_all = (unsigned short*)(bufC + (size_t)CBS * CD);  // bf16
    float* l_all  = (float*)(o_all + (size_t)CR * CBHS * CDH);
    int* buckets  = (int*)(l_all + (size_t)CR * CBHS);
    int* sorted   = buckets + (size_t)CR * CBHS;
    unsigned short* WvT   = (unsigned short*)(sorted + (size_t)CR * CBHS);
    unsigned short* WoT   = WvT + (size_t)CD * CD;
    unsigned short* W1T   = WoT + (size_t)CD * CD;             // [DFF][D]
    unsigned short* W2T   = W1T + (size_t)CD * CDFF;           // [D][DFF]
    unsigned short* WqkTh = W2T + (size_t)CD * CDFF;
    unsigned short* WqkTl = WqkTh + (size_t)CD * CD;
    unsigned short* ffh16 = (unsigned short*)bufB;             // aliases qk+v (dead by step 10)
    unsigned short* attnout16 = bufA16;                        // reuse (ln1 dead)
    unsigned short* lnY16 = bufA16;                            // reuse again
    float* y1 = (float*)d_out;
    float* y2 = y1 + (size_t)CBS * CD;

    // 0. weight transposes (fp32 -> bf16, [K][N] -> [N][K]); Wqk gets hi+lo
    wtrans_kernel<<<dim3(CD / 64, CD / 64), 256, 0, stream>>>(Wqk, WqkTh, WqkTl, CD, CD);
    wtrans_kernel<<<dim3(CD / 64, CD / 64), 256, 0, stream>>>(Wv, WvT, nullptr, CD, CD);
    wtrans_kernel<<<dim3(CD / 64, CD / 64), 256, 0, stream>>>(Wo, WoT, nullptr, CD, CD);
    wtrans_kernel<<<dim3(CDFF / 64, CD / 64), 256, 0, stream>>>(W1, W1T, nullptr, CD, CDFF);
    wtrans_kernel<<<dim3(CD / 64, CDFF / 64), 256, 0, stream>>>(W2, W2T, nullptr, CDFF, CD);
    // 1. ln(x2) -> bf16 hi + lo
    ln_kernel<<<CBS, 256, 0, stream>>>(x2, ln1g, ln1b, bufA16, bufA16lo);
    // 2. qk projection: split-bf16 MFMA -> fp32 (bucketing) + bf16 (attn)
    gemm_bf16split<64><<<dim3(CD / 128, CBS / 64), 256, 0, stream>>>(
        bufA16, bufA16lo, WqkTh, WqkTl, bufB, qk16, CBS, CD, CD);
    // 3. v projection (bf16 MFMA, bf16 out)
    gemm_bf16<5, 64><<<dim3(CD / 128, CBS / 64), 256, 0, stream>>>(
        bufA16, WvT, nullptr, nullptr, v16, CBS, CD, CD);
    // 4. LSH rotation GEMM + fused argmax -> buckets (fp32)
    gemm_f32<4><<<dim3(1, CBHS / 128), 256, 0, stream>>>(bufB, rot, (float*)buckets, CBHS, 128, 64);
    // 5. stable counting sort per (r,b,h)
    sort_kernel<<<CR * CB * CH, 64, 0, stream>>>(buckets, sorted);
    // 6. chunked masked attention (bf16 MFMA, bf16 inputs)
    attn_kernel<<<dim3(CNCH, CR, CB * CH), 256, 0, stream>>>(qk16, v16, buckets, sorted, o_all, l_all);
    // 7. round-weighted combine -> attnout bf16
    combine_kernel<<<(CBHS * CDH) / 256, 256, 0, stream>>>(o_all, l_all, attnout16);
    // 8. y1 = attnout @ Wo + x1 (bf16 MFMA, residual epilogue)
    gemm_bf16<3, 64><<<dim3(CD / 128, CBS / 64), 256, 0, stream>>>(
        attnout16, WoT, nullptr, x1, y1, CBS, CD, CD);
    // 9. ln(y1) -> bf16 only
    ln_kernel<<<CBS, 256, 0, stream>>>(y1, ln2g, ln2b, lnY16, nullptr);
    // 10. ffh = relu(ln_y1 @ W1 + bf1) -> bf16
    gemm_bf16<1, 128><<<dim3(CDFF / 128, CBS / 128), 256, 0, stream>>>(
        lnY16, W1T, bf1, nullptr, ffh16, CBS, CDFF, CD);
    // 11. y2 = ffh @ W2 + bf2 + x2 (fp32 out)
    gemm_bf16<2, 64><<<dim3(CD / 128, CBS / 64), 256, 0, stream>>>(
        ffh16, W2T, bf2, x2, y2, CBS, CD, CDFF);
}

// Round 2
// 643.280 us; speedup vs baseline: 1.1108x; 1.0190x over previous
//
#include <hip/hip_runtime.h>
#include <hip/hip_bf16.h>
#include <math.h>

// Problem constants
constexpr int CB   = 2;      // batch
constexpr int CS   = 4096;   // seq
constexpr int CD   = 1024;   // d_model
constexpr int CH   = 16;     // heads
constexpr int CDH  = 64;     // head dim
constexpr int CR   = 4;      // hash rounds
constexpr int CC   = 64;     // chunk length
constexpr int CNCH = 64;     // num chunks
constexpr int CDFF = 4096;
constexpr int CBS  = CB * CS;        // 8192 rows
constexpr int CBHS = CB * CH * CS;   // 131072

typedef __attribute__((ext_vector_type(8))) short short8;
typedef __attribute__((ext_vector_type(4))) short short4v;
typedef __attribute__((ext_vector_type(4))) float f32x4;

// HW bf16 conversion: gfx950 lowers fptrunc f32->bf16 to v_cvt_pk_bf16_f32.
__device__ inline unsigned short f2bf(float f) {
    __bf16 h = (__bf16)f;
    union { __bf16 h; unsigned short u; } c; c.h = h;
    return c.u;
}
// paired conversion -> one packed u32 (compiler fuses to single v_cvt_pk_bf16_f32)
__device__ inline unsigned int cvt2(float a, float b) {
    return (unsigned int)f2bf(a) | ((unsigned int)f2bf(b) << 16);
}
__device__ inline float bf2f(unsigned short h) {
    union { float f; unsigned int u; } a; a.u = ((unsigned int)h) << 16; return a.f;
}

#define AS3 __attribute__((address_space(3)))
#define AS1 __attribute__((address_space(1)))
__device__ inline void gload16(const unsigned short* g, unsigned short* l) {
    __builtin_amdgcn_global_load_lds((const AS1 unsigned int*)g,
                                     (AS3 unsigned int*)l, 16, 0, 0);
}

// 8-short load from 8B-aligned (not necessarily 16B-aligned) LDS address
__device__ inline short8 ld_short8_u(const unsigned short* p) {
    short4v a = *(const short4v*)p;
    short4v b = *(const short4v*)(p + 4);
    short8 r;
    r[0] = a[0]; r[1] = a[1]; r[2] = a[2]; r[3] = a[3];
    r[4] = b[0]; r[5] = b[1]; r[6] = b[2]; r[7] = b[3];
    return r;
}

// ---------------- LayerNorm: one block per row; bf16 hi (+ optional lo) -----
__global__ __launch_bounds__(256) void ln_kernel(const float* __restrict__ x,
        const float* __restrict__ g, const float* __restrict__ bta,
        unsigned short* __restrict__ out16, unsigned short* __restrict__ out16lo) {
    int row = blockIdx.x;
    int t = threadIdx.x;
    const float* xr = x + (size_t)row * CD;
    float4 v = *(const float4*)(xr + t * 4);
    float s  = v.x + v.y + v.z + v.w;
    float ss = v.x * v.x + v.y * v.y + v.z * v.z + v.w * v.w;
    #pragma unroll
    for (int off = 1; off < 64; off <<= 1) {
        s  += __shfl_xor(s, off);
        ss += __shfl_xor(ss, off);
    }
    __shared__ float ws_[4], wss_[4];
    int wid = t >> 6;
    if ((t & 63) == 0) { ws_[wid] = s; wss_[wid] = ss; }
    __syncthreads();
    s  = ws_[0] + ws_[1] + ws_[2] + ws_[3];
    ss = wss_[0] + wss_[1] + wss_[2] + wss_[3];
    float mean = s * (1.0f / CD);
    float var  = ss * (1.0f / CD) - mean * mean;
    float rstd = rsqrtf(var + 1e-5f);
    float4 gv = *(const float4*)(g + t * 4);
    float4 bv = *(const float4*)(bta + t * 4);
    float4 o;
    o.x = (v.x - mean) * rstd * gv.x + bv.x;
    o.y = (v.y - mean) * rstd * gv.y + bv.y;
    o.z = (v.z - mean) * rstd * gv.z + bv.z;
    o.w = (v.w - mean) * rstd * gv.w + bv.w;
    ushort4 h; h.x = f2bf(o.x); h.y = f2bf(o.y); h.z = f2bf(o.z); h.w = f2bf(o.w);
    *(ushort4*)(out16 + (size_t)row * CD + t * 4) = h;
    if (out16lo) {
        ushort4 lo;
        lo.x = f2bf(o.x - bf2f(h.x)); lo.y = f2bf(o.y - bf2f(h.y));
        lo.z = f2bf(o.z - bf2f(h.z)); lo.w = f2bf(o.w - bf2f(h.w));
        *(ushort4*)(out16lo + (size_t)row * CD + t * 4) = lo;
    }
}

// ------- weight transpose + fp32->bf16 (hi + optional lo): W[K][N]->WT[N][K]
__global__ __launch_bounds__(256) void wtrans_kernel(const float* __restrict__ W,
        unsigned short* __restrict__ WT, unsigned short* __restrict__ WTlo,
        int K, int N) {
    __shared__ float tile[64][65];
    int n0 = blockIdx.x * 64, k0 = blockIdx.y * 64;
    int tid = threadIdx.x;
    int r = tid >> 4, c4 = tid & 15;
    #pragma unroll
    for (int it = 0; it < 4; ++it) {
        int row = r + it * 16;
        float4 v = *(const float4*)(W + (size_t)(k0 + row) * N + n0 + c4 * 4);
        tile[row][c4 * 4 + 0] = v.x; tile[row][c4 * 4 + 1] = v.y;
        tile[row][c4 * 4 + 2] = v.z; tile[row][c4 * 4 + 3] = v.w;
    }
    __syncthreads();
    #pragma unroll
    for (int it = 0; it < 4; ++it) {
        int nrow = r + it * 16;
        float f0 = tile[c4 * 4 + 0][nrow], f1 = tile[c4 * 4 + 1][nrow];
        float f2 = tile[c4 * 4 + 2][nrow], f3 = tile[c4 * 4 + 3][nrow];
        ushort4 h;
        h.x = f2bf(f0); h.y = f2bf(f1); h.z = f2bf(f2); h.w = f2bf(f3);
        *(ushort4*)(WT + (size_t)(n0 + nrow) * K + k0 + c4 * 4) = h;
        if (WTlo) {
            ushort4 lo;
            lo.x = f2bf(f0 - bf2f(h.x)); lo.y = f2bf(f1 - bf2f(h.y));
            lo.z = f2bf(f2 - bf2f(h.z)); lo.w = f2bf(f3 - bf2f(h.w));
            *(ushort4*)(WTlo + (size_t)(n0 + nrow) * K + k0 + c4 * 4) = lo;
        }
    }
}

// ---------------- bf16 MFMA GEMM: C[M][N] = A[M][K] @ BT[N][K]^T ------------
// BM = 128 or 64 (N-tile fixed at 128); BK = 32 or 64 (K cols per barrier).
// BK=64 stages two 32-col halves per barrier: halves the barrier count and
// doubles MFMA per drain (the BM=64/BK=32 shape was barrier-bound: MfmaUtil
// 26%, VALU 29%, HBM 13%). XCD-chunked block swizzle throughout.
template<int EPI, int BM, int BK>
__global__ __launch_bounds__(256) void gemm_bf16(const unsigned short* __restrict__ A,
        const unsigned short* __restrict__ BT, const float* __restrict__ bias,
        const float* __restrict__ res, void* __restrict__ outp,
        int M, int N, int K) {
    constexpr int NH  = BK / 32;   // 32-col halves per K-step
    constexpr int SA  = BM / 64;   // A-staging chunks per wave per half
    constexpr int MI2 = BM / 32;   // A fragments per wave
    __shared__ __align__(16) unsigned short As[NH * BM * 32];
    __shared__ __align__(16) unsigned short Bs[NH * 128 * 32];
    int tid = threadIdx.x;
    int w = tid >> 6, l = tid & 63;
    // XCD-aware chunked swizzle (bijective since nwg % 8 == 0 for all launches)
    int nwg = gridDim.x * gridDim.y;
    int lid = blockIdx.y * gridDim.x + blockIdx.x;
    if (!(nwg & 7)) lid = (lid & 7) * (nwg >> 3) + (lid >> 3);
    int m0 = (lid / gridDim.x) * BM, n0 = (lid % gridDim.x) * 128;
    int wm = (w >> 1) * (BM / 2), wn = (w & 1) * 64;

    const unsigned short* gA[SA]; const unsigned short* gB[2];
    unsigned short* ldsA[SA]; unsigned short* ldsB[2];
    int gchunk = (l & 3) ^ ((l >> 3) & 3);
    #pragma unroll
    for (int s = 0; s < SA; ++s) {
        int j = w * SA + s;
        int R = j * 16 + (l >> 2);
        gA[s] = A + (size_t)(m0 + R) * K + gchunk * 8;
        ldsA[s] = As + j * 512;
    }
    #pragma unroll
    for (int s = 0; s < 2; ++s) {
        int j = w * 2 + s;
        int R = j * 16 + (l >> 2);
        gB[s] = BT + (size_t)(n0 + R) * K + gchunk * 8;
        ldsB[s] = Bs + j * 512;
    }
    int p = (l >> 4) ^ (((l & 15) >> 1) & 3);
    int aoff = (wm + (l & 15)) * 32 + p * 8;
    int boff = (wn + (l & 15)) * 32 + p * 8;

    f32x4 acc[MI2][4];
    #pragma unroll
    for (int i = 0; i < MI2; i++)
        #pragma unroll
        for (int j = 0; j < 4; j++) acc[i][j] = (f32x4)(0.f);

    for (int k0 = 0; k0 < K; k0 += BK) {
        #pragma unroll
        for (int h = 0; h < NH; ++h) {
            #pragma unroll
            for (int s = 0; s < SA; ++s)
                gload16(gA[s] + k0 + h * 32, ldsA[s] + h * (BM * 32));
            gload16(gB[0] + k0 + h * 32, ldsB[0] + h * (128 * 32));
            gload16(gB[1] + k0 + h * 32, ldsB[1] + h * (128 * 32));
        }
        __syncthreads();
        #pragma unroll
        for (int h = 0; h < NH; ++h) {
            short8 af[MI2], bf[4];
            #pragma unroll
            for (int im = 0; im < MI2; ++im)
                af[im] = *(const short8*)(As + h * (BM * 32) + aoff + im * 512);
            #pragma unroll
            for (int in = 0; in < 4; ++in)
                bf[in] = *(const short8*)(Bs + h * (128 * 32) + boff + in * 512);
            #pragma unroll
            for (int im = 0; im < MI2; ++im)
                #pragma unroll
                for (int in = 0; in < 4; ++in)
                    acc[im][in] = __builtin_amdgcn_mfma_f32_16x16x32_bf16(
                        af[im], bf[in], acc[im][in], 0, 0, 0);
        }
        __syncthreads();
    }

    float bv[4];
    if (EPI == 1 || EPI == 2) {
        #pragma unroll
        for (int in = 0; in < 4; ++in) bv[in] = bias[n0 + wn + in * 16 + (l & 15)];
    }
    #pragma unroll
    for (int im = 0; im < MI2; ++im) {
        #pragma unroll
        for (int in = 0; in < 4; ++in) {
            int n = n0 + wn + in * 16 + (l & 15);
            #pragma unroll
            for (int r = 0; r < 4; ++r) {
                int m = m0 + wm + im * 16 + (l >> 4) * 4 + r;
                float v = acc[im][in][r];
                if (EPI == 1) {
                    v = fmaxf(v + bv[in], 0.f);
                    ((unsigned short*)outp)[(size_t)m * N + n] = f2bf(v);
                } else if (EPI == 5) {
                    ((unsigned short*)outp)[(size_t)m * N + n] = f2bf(v);
                } else {
                    if (EPI == 2) v += bv[in] + res[(size_t)m * N + n];
                    if (EPI == 3) v += res[(size_t)m * N + n];
                    ((float*)outp)[(size_t)m * N + n] = v;
                }
            }
        }
    }
}

// -------- split-bf16 MFMA GEMM (hi/lo): C = (Ah+Al) @ (Bh+Bl)^T -------------
// fp32 out (bucketing) + bf16 out (attention). acc = Ah@Bh + Al@Bh + Ah@Bl.
template<int BM>
__global__ __launch_bounds__(256) void gemm_bf16split(
        const unsigned short* __restrict__ Ah, const unsigned short* __restrict__ Al,
        const unsigned short* __restrict__ BTh, const unsigned short* __restrict__ BTl,
        float* __restrict__ outp, unsigned short* __restrict__ out16,
        int M, int N, int K) {
    constexpr int SA  = BM / 64;
    constexpr int MI2 = BM / 32;
    __shared__ __align__(16) unsigned short Ash[BM * 32];
    __shared__ __align__(16) unsigned short Asl[BM * 32];
    __shared__ __align__(16) unsigned short Bsh[128 * 32];
    __shared__ __align__(16) unsigned short Bsl[128 * 32];
    int tid = threadIdx.x;
    int w = tid >> 6, l = tid & 63;
    int nwg = gridDim.x * gridDim.y;
    int lid = blockIdx.y * gridDim.x + blockIdx.x;
    if (!(nwg & 7)) lid = (lid & 7) * (nwg >> 3) + (lid >> 3);
    int m0 = (lid / gridDim.x) * BM, n0 = (lid % gridDim.x) * 128;
    int wm = (w >> 1) * (BM / 2), wn = (w & 1) * 64;

    size_t goffA[SA]; size_t goffB[2];
    unsigned short* ldsAh[SA]; unsigned short* ldsAl[SA];
    unsigned short* ldsBh[2]; unsigned short* ldsBl[2];
    int gchunk = (l & 3) ^ ((l >> 3) & 3);
    #pragma unroll
    for (int s = 0; s < SA; ++s) {
        int j = w * SA + s;
        int R = j * 16 + (l >> 2);
        goffA[s] = (size_t)(m0 + R) * K + gchunk * 8;
        ldsAh[s] = Ash + j * 512; ldsAl[s] = Asl + j * 512;
    }
    #pragma unroll
    for (int s = 0; s < 2; ++s) {
        int j = w * 2 + s;
        int R = j * 16 + (l >> 2);
        goffB[s] = (size_t)(n0 + R) * K + gchunk * 8;
        ldsBh[s] = Bsh + j * 512; ldsBl[s] = Bsl + j * 512;
    }
    int p = (l >> 4) ^ (((l & 15) >> 1) & 3);
    int aoff = (wm + (l & 15)) * 32 + p * 8;
    int boff = (wn + (l & 15)) * 32 + p * 8;

    f32x4 acc[MI2][4];
    #pragma unroll
    for (int i = 0; i < MI2; i++)
        #pragma unroll
        for (int j = 0; j < 4; j++) acc[i][j] = (f32x4)(0.f);

    for (int k0 = 0; k0 < K; k0 += 32) {
        #pragma unroll
        for (int s = 0; s < SA; ++s) {
            gload16(Ah + goffA[s] + k0, ldsAh[s]);
            gload16(Al + goffA[s] + k0, ldsAl[s]);
        }
        #pragma unroll
        for (int s = 0; s < 2; ++s) {
            gload16(BTh + goffB[s] + k0, ldsBh[s]);
            gload16(BTl + goffB[s] + k0, ldsBl[s]);
        }
        __syncthreads();
        short8 afh[MI2], afl[MI2], bfh[4], bfl[4];
        #pragma unroll
        for (int im = 0; im < MI2; ++im) {
            afh[im] = *(const short8*)(Ash + aoff + im * 512);
            afl[im] = *(const short8*)(Asl + aoff + im * 512);
        }
        #pragma unroll
        for (int in = 0; in < 4; ++in) {
            bfh[in] = *(const short8*)(Bsh + boff + in * 512);
            bfl[in] = *(const short8*)(Bsl + boff + in * 512);
        }
        #pragma unroll
        for (int im = 0; im < MI2; ++im)
            #pragma unroll
            for (int in = 0; in < 4; ++in) {
                acc[im][in] = __builtin_amdgcn_mfma_f32_16x16x32_bf16(
                    afh[im], bfh[in], acc[im][in], 0, 0, 0);
                acc[im][in] = __builtin_amdgcn_mfma_f32_16x16x32_bf16(
                    afl[im], bfh[in], acc[im][in], 0, 0, 0);
                acc[im][in] = __builtin_amdgcn_mfma_f32_16x16x32_bf16(
                    afh[im], bfl[in], acc[im][in], 0, 0, 0);
            }
        __syncthreads();
    }

    #pragma unroll
    for (int im = 0; im < MI2; ++im)
        #pragma unroll
        for (int in = 0; in < 4; ++in) {
            int n = n0 + wn + in * 16 + (l & 15);
            #pragma unroll
            for (int r = 0; r < 4; ++r) {
                int m = m0 + wm + im * 16 + (l >> 4) * 4 + r;
                float v = acc[im][in][r];
                outp[(size_t)m * N + n] = v;
                out16[(size_t)m * N + n] = f2bf(v);
            }
        }
}

// ---------------- fp32 tiled GEMM (rotation + bucket argmax only) -----------
template<int EPI>
__global__ __launch_bounds__(256) void gemm_f32(const float* __restrict__ A,
        const float* __restrict__ W, float* __restrict__ out,
        int M, int N, int K) {
    __shared__ __align__(16) float As[16][132];
    __shared__ __align__(16) float Bs[16][132];
    int tid = threadIdx.x;
    int n0 = blockIdx.x * 128;
    int m0 = blockIdx.y * 128;
    int ty = tid >> 4, tx = tid & 15;
    float acc[8][8];
    #pragma unroll
    for (int i = 0; i < 8; i++)
        #pragma unroll
        for (int j = 0; j < 8; j++) acc[i][j] = 0.f;

    for (int k0 = 0; k0 < K; k0 += 16) {
        #pragma unroll
        for (int it = 0; it < 2; ++it) {
            int f4 = tid + it * 256;
            int row = f4 >> 2, c4 = f4 & 3;
            float4 av = *(const float4*)(A + (size_t)(m0 + row) * K + k0 + c4 * 4);
            As[c4 * 4 + 0][row] = av.x;
            As[c4 * 4 + 1][row] = av.y;
            As[c4 * 4 + 2][row] = av.z;
            As[c4 * 4 + 3][row] = av.w;
        }
        #pragma unroll
        for (int it = 0; it < 2; ++it) {
            int f4 = tid + it * 256;
            int kr = f4 >> 5, c4 = f4 & 31;
            *(float4*)(&Bs[kr][c4 * 4]) =
                *(const float4*)(W + (size_t)(k0 + kr) * N + n0 + c4 * 4);
        }
        __syncthreads();
        #pragma unroll
        for (int kk = 0; kk < 16; ++kk) {
            float4 a0 = *(const float4*)(&As[kk][ty * 8]);
            float4 a1 = *(const float4*)(&As[kk][ty * 8 + 4]);
            float4 b0 = *(const float4*)(&Bs[kk][tx * 8]);
            float4 b1 = *(const float4*)(&Bs[kk][tx * 8 + 4]);
            float am[8] = {a0.x, a0.y, a0.z, a0.w, a1.x, a1.y, a1.z, a1.w};
            float bn[8] = {b0.x, b0.y, b0.z, b0.w, b1.x, b1.y, b1.z, b1.w};
            #pragma unroll
            for (int i = 0; i < 8; i++)
                #pragma unroll
                for (int j = 0; j < 8; j++)
                    acc[i][j] = fmaf(am[i], bn[j], acc[i][j]);
        }
        __syncthreads();
    }

    if (EPI == 4) {
        int* ibuck = (int*)out;
        int q = tx & 3, r = tx >> 2;      // col = r*32 + q*8 + j
        #pragma unroll
        for (int i = 0; i < 8; i++) {
            int m = m0 + ty * 8 + i;
            float bestP = -3.4e38f, bestN = -3.4e38f;
            int biP = 0, biN = 0;
            #pragma unroll
            for (int j = 0; j < 8; j++) {
                float v = acc[i][j];
                if ( v > bestP) { bestP =  v; biP = q * 8 + j; }
                if (-v > bestN) { bestN = -v; biN = q * 8 + j; }
            }
            #pragma unroll
            for (int off = 1; off < 4; off <<= 1) {
                float oP = __shfl_xor(bestP, off); int oiP = __shfl_xor(biP, off);
                float oN = __shfl_xor(bestN, off); int oiN = __shfl_xor(biN, off);
                if (oP > bestP || (oP == bestP && oiP < biP)) { bestP = oP; biP = oiP; }
                if (oN > bestN || (oN == bestN && oiN < biN)) { bestN = oN; biN = oiN; }
            }
            if (q == 0) {
                int bi = (bestP >= bestN) ? biP : (biN + 32);
                int hh = m & 15, ss2 = (m >> 4) & (CS - 1), bb2 = m >> 16;
                ibuck[((size_t)((r * CB + bb2) * CH + hh)) * CS + ss2] = bi;
            }
        }
        return;
    }

    #pragma unroll
    for (int i = 0; i < 8; i++) {
        int m = m0 + ty * 8 + i;
        #pragma unroll
        for (int j4 = 0; j4 < 2; j4++) {
            int n = n0 + tx * 8 + j4 * 4;
            float4 v;
            v.x = acc[i][j4 * 4 + 0]; v.y = acc[i][j4 * 4 + 1];
            v.z = acc[i][j4 * 4 + 2]; v.w = acc[i][j4 * 4 + 3];
            *(float4*)(out + (size_t)m * N + n) = v;
        }
    }
}

// ---------------- stable counting sort per (r,b,h): one wave ----------------
__global__ __launch_bounds__(64) void sort_kernel(const int* __restrict__ buckets,
                                                  int* __restrict__ sorted_pos) {
    int g = blockIdx.x;                  // rbh
    const int* bk = buckets + (size_t)g * CS;
    __shared__ int hist[64][65];
    __shared__ int bstart[64];
    int t = threadIdx.x;
    #pragma unroll
    for (int i = 0; i < 64; i++) hist[t][i] = 0;
    __syncthreads();
    int base = t * 64;
    for (int i = 0; i < 64; i++) { int b = bk[base + i]; hist[t][b]++; }
    __syncthreads();
    int run = 0;
    for (int tt = 0; tt < 64; tt++) {
        int c = hist[tt][t];
        hist[tt][t] = run;
        run += c;
    }
    int x = run;
    #pragma unroll
    for (int off = 1; off < 64; off <<= 1) {
        int y = __shfl_up(x, off);
        if (t >= off) x += y;
    }
    bstart[t] = x - run;
    __syncthreads();
    for (int i = 0; i < 64; i++) {
        int b = bk[base + i];
        int rank = bstart[b] + hist[t][b];
        hist[t][b]++;
        sorted_pos[(size_t)g * CS + rank] = base + i;
    }
}

// ---------------- chunked LSH attention (bf16 MFMA, bf16 inputs) ------------
__global__ __launch_bounds__(256) void attn_kernel(const unsigned short* __restrict__ qk16,
        const unsigned short* __restrict__ v16, const int* __restrict__ buckets,
        const int* __restrict__ sorted, unsigned short* __restrict__ o_all,
        float* __restrict__ l_all) {
    int n  = blockIdx.x;
    int r  = blockIdx.y;
    int bh = blockIdx.z;
    int b = bh >> 4, h = bh & 15;
    int rbh = (r * CB + b) * CH + h;
    int tid = threadIdx.x;
    int w = tid >> 6, l = tid & 63;
    int l4 = l & 15, qd = l >> 4;

    __shared__ int pk[128];
    __shared__ int bkk[128];
    __shared__ __align__(16) unsigned short Ks[128 * 72];   // K-hat [kk][d]
    __shared__ __align__(16) unsigned short Ps[64 * 132];   // P [m][kk]
    __shared__ __align__(16) unsigned short VsT[64 * 132];  // V^T [d][kk]

    int prev = (n + CNCH - 1) & (CNCH - 1);
    if (tid < 128) {
        int i = tid & 63;
        int ch = (tid < 64) ? n : prev;
        int p = sorted[(size_t)rbh * CS + ch * CC + i];
        pk[tid] = p;
        bkk[tid] = buckets[(size_t)rbh * CS + p];
    }
    __syncthreads();

    const unsigned short* qbase = qk16 + (size_t)b * CS * CD + h * 64;
    const unsigned short* vbase = v16  + (size_t)b * CS * CD + h * 64;

    // K staging: load bf16 qk row, L2-normalize, store bf16 (paired cvt)
    #pragma unroll
    for (int it = 0; it < 8; ++it) {
        int f4 = tid + it * 256;            // 0..2047
        int kk = f4 >> 4, d4 = f4 & 15;
        ushort4 hv = *(const ushort4*)(qbase + (size_t)pk[kk] * CD + d4 * 4);
        float x0 = bf2f(hv.x), x1 = bf2f(hv.y), x2 = bf2f(hv.z), x3 = bf2f(hv.w);
        float ss = x0 * x0 + x1 * x1 + x2 * x2 + x3 * x3;
        ss += __shfl_xor(ss, 1); ss += __shfl_xor(ss, 2);
        ss += __shfl_xor(ss, 4); ss += __shfl_xor(ss, 8);
        float rn = __builtin_amdgcn_rcpf(sqrtf(ss) + 1e-6f);
        uint2 kp;
        kp.x = cvt2(x0 * rn, x1 * rn);
        kp.y = cvt2(x2 * rn, x3 * rn);
        *(uint2*)&Ks[kk * 72 + d4 * 4] = kp;
    }
    // V staging: already bf16 — pack two rows per u32, zero conversions
    #pragma unroll
    for (int it = 0; it < 16; ++it) {
        int kkp = w * 16 + it;              // 0..63 (pair index)
        int r0 = pk[2 * kkp], r1 = pk[2 * kkp + 1];
        unsigned int u0 = vbase[(size_t)r0 * CD + l];
        unsigned int u1 = vbase[(size_t)r1 * CD + l];
        *(unsigned int*)&VsT[l * 132 + 2 * kkp] = u0 | (u1 << 16);
    }
    // Q fragments: direct bf16 16B loads, zero conversions
    int mstrip = w * 16;
    const unsigned short* qptr = qbase + (size_t)pk[mstrip + l4] * CD + qd * 8;
    short8 afA = *(const short8*)(qptr);
    short8 afB = *(const short8*)(qptr + 32);
    __syncthreads();

    f32x4 sa[8];
    #pragma unroll
    for (int t = 0; t < 8; ++t) sa[t] = (f32x4)(0.f);
    #pragma unroll
    for (int t = 0; t < 8; ++t) {
        const unsigned short* kb = &Ks[(t * 16 + l4) * 72 + qd * 8];
        short8 b0 = *(const short8*)(kb);
        short8 b1 = *(const short8*)(kb + 32);
        sa[t] = __builtin_amdgcn_mfma_f32_16x16x32_bf16(afA, b0, sa[t], 0, 0, 0);
        sa[t] = __builtin_amdgcn_mfma_f32_16x16x32_bf16(afB, b1, sa[t], 0, 0, 0);
    }

    int rowb[4], rowp[4];
    #pragma unroll
    for (int rr = 0; rr < 4; ++rr) {
        int m = mstrip + 4 * qd + rr;
        rowb[rr] = bkk[m]; rowp[rr] = pk[m];
    }
    float mx[4] = {-3.4e38f, -3.4e38f, -3.4e38f, -3.4e38f};
    #pragma unroll
    for (int t = 0; t < 8; ++t) {
        int cb = bkk[t * 16 + l4], cp = pk[t * 16 + l4];
        #pragma unroll
        for (int rr = 0; rr < 4; ++rr) {
            float v = sa[t][rr] * 0.125f;
            if (rowb[rr] != cb) v = -1e9f;
            if (rowp[rr] == cp) v = -1e5f;
            sa[t][rr] = v;
            mx[rr] = fmaxf(mx[rr], v);
        }
    }
    #pragma unroll
    for (int rr = 0; rr < 4; ++rr) {
        mx[rr] = fmaxf(mx[rr], __shfl_xor(mx[rr], 1));
        mx[rr] = fmaxf(mx[rr], __shfl_xor(mx[rr], 2));
        mx[rr] = fmaxf(mx[rr], __shfl_xor(mx[rr], 4));
        mx[rr] = fmaxf(mx[rr], __shfl_xor(mx[rr], 8));
    }
    float sum[4] = {0.f, 0.f, 0.f, 0.f};
    #pragma unroll
    for (int t = 0; t < 8; ++t)
        #pragma unroll
        for (int rr = 0; rr < 4; ++rr) {
            float e = __expf(sa[t][rr] - mx[rr]);
            sa[t][rr] = e;
            sum[rr] += e;
        }
    #pragma unroll
    for (int rr = 0; rr < 4; ++rr) {
        sum[rr] += __shfl_xor(sum[rr], 1);
        sum[rr] += __shfl_xor(sum[rr], 2);
        sum[rr] += __shfl_xor(sum[rr], 4);
        sum[rr] += __shfl_xor(sum[rr], 8);
    }
    if (l4 == 0) {
        #pragma unroll
        for (int rr = 0; rr < 4; ++rr)
            l_all[(size_t)rbh * CS + rowp[rr]] = mx[rr] + __logf(sum[rr]);
    }

    float rs[4];
    #pragma unroll
    for (int rr = 0; rr < 4; ++rr) rs[rr] = __builtin_amdgcn_rcpf(sum[rr]);
    // P -> bf16 via paired conversions (rows rr0/rr1 and rr2/rr3 share a cvt)
    #pragma unroll
    for (int t = 0; t < 8; ++t) {
        unsigned int a01 = cvt2(sa[t][0] * rs[0], sa[t][1] * rs[1]);
        unsigned int a23 = cvt2(sa[t][2] * rs[2], sa[t][3] * rs[3]);
        int base = (mstrip + 4 * qd) * 132 + t * 16 + l4;
        Ps[base]       = (unsigned short)(a01 & 0xffffu);
        Ps[base + 132] = (unsigned short)(a01 >> 16);
        Ps[base + 264] = (unsigned short)(a23 & 0xffffu);
        Ps[base + 396] = (unsigned short)(a23 >> 16);
    }

    f32x4 oa[4];
    #pragma unroll
    for (int nt = 0; nt < 4; ++nt) oa[nt] = (f32x4)(0.f);
    #pragma unroll
    for (int ks = 0; ks < 4; ++ks) {
        short8 ap = ld_short8_u(&Ps[(mstrip + l4) * 132 + ks * 32 + qd * 8]);
        #pragma unroll
        for (int nt = 0; nt < 4; ++nt) {
            short8 bv = ld_short8_u(&VsT[(nt * 16 + l4) * 132 + ks * 32 + qd * 8]);
            oa[nt] = __builtin_amdgcn_mfma_f32_16x16x32_bf16(ap, bv, oa[nt], 0, 0, 0);
        }
    }
    size_t ob = (size_t)rbh * CS;
    #pragma unroll
    for (int nt = 0; nt < 4; ++nt) {
        unsigned int a01 = cvt2(oa[nt][0], oa[nt][1]);
        unsigned int a23 = cvt2(oa[nt][2], oa[nt][3]);
        o_all[(ob + rowp[0]) * CDH + nt * 16 + l4] = (unsigned short)(a01 & 0xffffu);
        o_all[(ob + rowp[1]) * CDH + nt * 16 + l4] = (unsigned short)(a01 >> 16);
        o_all[(ob + rowp[2]) * CDH + nt * 16 + l4] = (unsigned short)(a23 & 0xffffu);
        o_all[(ob + rowp[3]) * CDH + nt * 16 + l4] = (unsigned short)(a23 >> 16);
    }
}

// ---------------- combine rounds: softmax over R of logsumexp; bf16 out -----
__global__ __launch_bounds__(256) void combine_kernel(const unsigned short* __restrict__ o_all,
        const float* __restrict__ l_all, unsigned short* __restrict__ attnout16) {
    int idx = blockIdx.x * 256 + threadIdx.x;
    int d = idx & 63, bhs = idx >> 6;
    int s2 = bhs & (CS - 1), bh = bhs >> 12, h = bh & 15, b = bh >> 4;
    float lr[4];
    #pragma unroll
    for (int r = 0; r < CR; r++) lr[r] = l_all[(size_t)r * CBHS + bhs];
    float m = fmaxf(fmaxf(lr[0], lr[1]), fmaxf(lr[2], lr[3]));
    float w[4], sum = 0.f;
    #pragma unroll
    for (int r = 0; r < CR; r++) { w[r] = __expf(lr[r] - m); sum += w[r]; }
    float acc = 0.f;
    #pragma unroll
    for (int r = 0; r < CR; r++)
        acc += w[r] * bf2f(o_all[((size_t)r * CBHS + bhs) * CDH + d]);
    acc *= __builtin_amdgcn_rcpf(sum);
    attnout16[((size_t)(b * CS + s2)) * CD + h * 64 + d] = f2bf(acc);
}

extern "C" void kernel_launch(void* const* d_in, const int* in_sizes, int n_in,
                              void* d_out, int out_size, void* d_ws, size_t ws_size,
                              hipStream_t stream) {
    const float* x1   = (const float*)d_in[0];
    const float* x2   = (const float*)d_in[1];
    const float* Wqk  = (const float*)d_in[2];
    const float* Wv   = (const float*)d_in[3];
    const float* Wo   = (const float*)d_in[4];
    const float* ln1g = (const float*)d_in[5];
    const float* ln1b = (const float*)d_in[6];
    const float* W1   = (const float*)d_in[7];
    const float* bf1  = (const float*)d_in[8];
    const float* W2   = (const float*)d_in[9];
    const float* bf2  = (const float*)d_in[10];
    const float* ln2g = (const float*)d_in[11];
    const float* ln2b = (const float*)d_in[12];
    const float* rot  = (const float*)d_in[13];   // [64][128] row-major

    unsigned short* bufA16   = (unsigned short*)d_ws;          // ln1 hi bf16
    unsigned short* bufA16lo = bufA16 + (size_t)CBS * CD;      // ln1 lo bf16
    float* bufB = (float*)(bufA16lo + (size_t)CBS * CD);       // qk fp32
    float* bufC = bufB + (size_t)CBS * CD;                     // v16 + qk16 (bf16)
    unsigned short* v16  = (unsigned short*)bufC;              // v bf16
    unsigned short* qk16 = v16 + (size_t)CBS * CD;             // qk bf16
    unsigned short* o_all = (unsigned short*)(bufC + (size_t)CBS * CD);  // bf16
    float* l_all  = (float*)(o_all + (size_t)CR * CBHS * CDH);
    int* buckets  = (int*)(l_all + (size_t)CR * CBHS);
    int* sorted   = buckets + (size_t)CR * CBHS;
    unsigned short* WvT   = (unsigned short*)(sorted + (size_t)CR * CBHS);
    unsigned short* WoT   = WvT + (size_t)CD * CD;
    unsigned short* W1T   = WoT + (size_t)CD * CD;             // [DFF][D]
    unsigned short* W2T   = W1T + (size_t)CD * CDFF;           // [D][DFF]
    unsigned short* WqkTh = W2T + (size_t)CD * CDFF;
    unsigned short* WqkTl = WqkTh + (size_t)CD * CD;
    unsigned short* ffh16 = (unsigned short*)bufB;             // aliases qk+v (dead by step 10)
    unsigned short* attnout16 = bufA16;                        // reuse (ln1 dead)
    unsigned short* lnY16 = bufA16;                            // reuse again
    float* y1 = (float*)d_out;
    float* y2 = y1 + (size_t)CBS * CD;

    // 0. weight transposes (fp32 -> bf16, [K][N] -> [N][K]); Wqk gets hi+lo
    wtrans_kernel<<<dim3(CD / 64, CD / 64), 256, 0, stream>>>(Wqk, WqkTh, WqkTl, CD, CD);
    wtrans_kernel<<<dim3(CD / 64, CD / 64), 256, 0, stream>>>(Wv, WvT, nullptr, CD, CD);
    wtrans_kernel<<<dim3(CD / 64, CD / 64), 256, 0, stream>>>(Wo, WoT, nullptr, CD, CD);
    wtrans_kernel<<<dim3(CDFF / 64, CD / 64), 256, 0, stream>>>(W1, W1T, nullptr, CD, CDFF);
    wtrans_kernel<<<dim3(CD / 64, CDFF / 64), 256, 0, stream>>>(W2, W2T, nullptr, CDFF, CD);
    // 1. ln(x2) -> bf16 hi + lo
    ln_kernel<<<CBS, 256, 0, stream>>>(x2, ln1g, ln1b, bufA16, bufA16lo);
    // 2. qk projection: split-bf16 MFMA -> fp32 (bucketing) + bf16 (attn)
    gemm_bf16split<64><<<dim3(CD / 128, CBS / 64), 256, 0, stream>>>(
        bufA16, bufA16lo, WqkTh, WqkTl, bufB, qk16, CBS, CD, CD);
    // 3. v projection (bf16 MFMA, bf16 out, BK=64)
    gemm_bf16<5, 64, 64><<<dim3(CD / 128, CBS / 64), 256, 0, stream>>>(
        bufA16, WvT, nullptr, nullptr, v16, CBS, CD, CD);
    // 4. LSH rotation GEMM + fused argmax -> buckets (fp32)
    gemm_f32<4><<<dim3(1, CBHS / 128), 256, 0, stream>>>(bufB, rot, (float*)buckets, CBHS, 128, 64);
    // 5. stable counting sort per (r,b,h)
    sort_kernel<<<CR * CB * CH, 64, 0, stream>>>(buckets, sorted);
    // 6. chunked masked attention (bf16 MFMA, bf16 inputs)
    attn_kernel<<<dim3(CNCH, CR, CB * CH), 256, 0, stream>>>(qk16, v16, buckets, sorted, o_all, l_all);
    // 7. round-weighted combine -> attnout bf16
    combine_kernel<<<(CBHS * CDH) / 256, 256, 0, stream>>>(o_all, l_all, attnout16);
    // 8. y1 = attnout @ Wo + x1 (bf16 MFMA, residual epilogue, BK=64)
    gemm_bf16<3, 64, 64><<<dim3(CD / 128, CBS / 64), 256, 0, stream>>>(
        attnout16, WoT, nullptr, x1, y1, CBS, CD, CD);
    // 9. ln(y1) -> bf16 only
    ln_kernel<<<CBS, 256, 0, stream>>>(y1, ln2g, ln2b, lnY16, nullptr);
    // 10. ffh = relu(ln_y1 @ W1 + bf1) -> bf16 (128-tile, BK=32: m97 shape)
    gemm_bf16<1, 128, 32><<<dim3(CDFF / 128, CBS / 128), 256, 0, stream>>>(
        lnY16, W1T, bf1, nullptr, ffh16, CBS, CDFF, CD);
    // 11. y2 = ffh @ W2 + bf2 + x2 (fp32 out, BK=64: halved barrier count)
    gemm_bf16<2, 64, 64><<<dim3(CD / 128, CBS / 64), 256, 0, stream>>>(
        ffh16, W2T, bf2, x2, y2, CBS, CD, CDFF);
}